// Round 2
// baseline (733.802 us; speedup 1.0000x reference)
//
#include <hip/hip_runtime.h>
#include <hip/hip_bf16.h>
#include <cmath>

#define BATCH 32
#define SEQLEN 512
#define NSAMP 1000
#define DMODEL 1024

typedef __bf16 bf16x8_t __attribute__((ext_vector_type(8)));
typedef float f32x4_t __attribute__((ext_vector_type(4)));

__device__ __forceinline__ unsigned pack_bf2(float lo, float hi) {
    unsigned ulo = __float_as_uint(lo);
    unsigned uhi = __float_as_uint(hi);
    ulo = (ulo + 0x7fffu + ((ulo >> 16) & 1u)) >> 16;
    uhi = (uhi + 0x7fffu + ((uhi >> 16) & 1u)) & 0xffff0000u;
    return (ulo & 0xffffu) | uhi;
}

// TF log-uniform sampler expected-count, log-domain.
// p = log((id+2)/(id+1))/log(NC+1) computed via log1p to avoid cancellation.
__device__ __forceinline__ float log_expected_count(int id) {
    float idf = (float)id;
    float p = log1pf(1.0f / (idf + 1.0f)) * 0.09242316f; // 1/ln(50001)
    return logf(-expm1f(1000.0f * log1pf(-p)));
}

#define STAGE(dst, f1, f2)                                                     \
    do {                                                                       \
        uint4 _u;                                                              \
        _u.x = pack_bf2((f1).x, (f1).y);                                       \
        _u.y = pack_bf2((f1).z, (f1).w);                                       \
        _u.z = pack_bf2((f2).x, (f2).y);                                       \
        _u.w = pack_bf2((f2).z, (f2).w);                                       \
        *(uint4*)(dst) = _u;                                                   \
    } while (0)

__global__ __launch_bounds__(256) void sampled_softmax_main(
    const float* __restrict__ h, const int* __restrict__ labels,
    const int* __restrict__ sids, const float* __restrict__ W,
    const float* __restrict__ bias, float* __restrict__ accum)
{
    // LDS: double-buffered bf16 A/B tiles (64x32 each), XOR-swizzled 16B chunks
    __shared__ __align__(16) unsigned short Albuf[2][64 * 32];
    __shared__ __align__(16) unsigned short Blbuf[2][64 * 32];
    __shared__ float logits[64 * 67];
    __shared__ int   tid_lds[64];
    __shared__ float true_lds[64];
    __shared__ int   srow_lds[64];
    __shared__ int   sid_lds[64];
    __shared__ float adj_lds[64];
    __shared__ float mpart[4][64];
    __shared__ float lpart[4][64];

    const int tile_t = blockIdx.x;   // 0..7
    const int bb     = blockIdx.y;   // 0..31
    const int t0     = tile_t * 64;
    const int tid    = threadIdx.x;
    const int w      = tid >> 6;     // wave 0..3
    const int lane   = tid & 63;
    const int lm     = lane & 15;
    const int q      = lane >> 4;

    if (tid < 64) tid_lds[tid] = labels[bb * SEQLEN + t0 + tid];
    __syncthreads();

    // ---- true logits: fp32 vector dot, one wave per 16 rows ----
    for (int i = 0; i < 16; ++i) {
        const int r = w * 16 + i;
        const int lab = tid_lds[r];
        const float4* hp = (const float4*)(h + ((size_t)(bb * SEQLEN + t0 + r)) * DMODEL);
        const float4* wp = (const float4*)(W + (size_t)lab * DMODEL);
        float s = 0.0f;
#pragma unroll
        for (int j = 0; j < 4; ++j) {
            float4 a = hp[lane + j * 64];
            float4 c = wp[lane + j * 64];
            s += a.x * c.x + a.y * c.y + a.z * c.z + a.w * c.w;
        }
#pragma unroll
        for (int off = 32; off > 0; off >>= 1) s += __shfl_xor(s, off, 64);
        if (lane == 0) true_lds[r] = s + bias[lab] - log_expected_count(lab);
    }

    float m_run = -INFINITY, l_run = 0.0f;

    // staging assignment: thread -> (row 0..63, 8-float chunk 0..3)
    const int row    = tid >> 2;
    const int cg     = tid & 3;
    const int wchunk = cg ^ (row & 3);           // XOR swizzle on write
    const int wr = w >> 1, wc = w & 1;           // wave 2x2 layout over 64x64
    const int ar0 = 32 * wr + lm;                // A frag row (ti=0)
    const int bc0 = 32 * wc + lm;                // B frag row (si=0)
    const int achunk = (q ^ (lm & 3)) * 8;       // XOR swizzle on frag read
    const float* aG = h + ((size_t)(bb * SEQLEN + t0 + row)) * DMODEL + cg * 8;

    for (int s0 = 0; s0 < NSAMP; s0 += 64) {
        const int scount = (NSAMP - s0 < 64) ? (NSAMP - s0) : 64;
        __syncthreads();   // protect sid/adj/logits reuse
        if (tid < 64) {
            const int s = s0 + tid;
            const int sv = (s < NSAMP) ? sids[bb * NSAMP + s] : 0;
            srow_lds[tid] = sv;
            sid_lds[tid]  = (s < NSAMP) ? sv : -1;
            adj_lds[tid]  = (s < NSAMP) ? (bias[sv] - log_expected_count(sv)) : 0.0f;
        }
        __syncthreads();

        const float* bG = W + (size_t)srow_lds[row] * DMODEL + cg * 8;

        f32x4_t acc00 = {0,0,0,0}, acc01 = {0,0,0,0};
        f32x4_t acc10 = {0,0,0,0}, acc11 = {0,0,0,0};

        // prologue: stage K-tile 0 into buffer 0
        {
            float4 a1 = *(const float4*)(aG);
            float4 a2 = *(const float4*)(aG + 4);
            float4 b1 = *(const float4*)(bG);
            float4 b2 = *(const float4*)(bG + 4);
            STAGE(&Albuf[0][row * 32 + wchunk * 8], a1, a2);
            STAGE(&Blbuf[0][row * 32 + wchunk * 8], b1, b2);
        }
        __syncthreads();

#pragma unroll 2
        for (int kt = 0; kt < 32; ++kt) {
            const int cur = kt & 1;
            float4 a1, a2, b1, b2;
            const bool more = (kt + 1) < 32;
            if (more) {   // prefetch next K-tile while MFMA runs on current
                const float* ap = aG + (kt + 1) * 32;
                const float* bp = bG + (kt + 1) * 32;
                a1 = *(const float4*)(ap);
                a2 = *(const float4*)(ap + 4);
                b1 = *(const float4*)(bp);
                b2 = *(const float4*)(bp + 4);
            }
            const unsigned short* Ab = Albuf[cur];
            const unsigned short* Bb = Blbuf[cur];
            bf16x8_t fa0 = *(const bf16x8_t*)(Ab + ar0 * 32 + achunk);
            bf16x8_t fa1 = *(const bf16x8_t*)(Ab + (ar0 + 16) * 32 + achunk);
            bf16x8_t fb0 = *(const bf16x8_t*)(Bb + bc0 * 32 + achunk);
            bf16x8_t fb1 = *(const bf16x8_t*)(Bb + (bc0 + 16) * 32 + achunk);
            acc00 = __builtin_amdgcn_mfma_f32_16x16x32_bf16(fa0, fb0, acc00, 0, 0, 0);
            acc01 = __builtin_amdgcn_mfma_f32_16x16x32_bf16(fa0, fb1, acc01, 0, 0, 0);
            acc10 = __builtin_amdgcn_mfma_f32_16x16x32_bf16(fa1, fb0, acc10, 0, 0, 0);
            acc11 = __builtin_amdgcn_mfma_f32_16x16x32_bf16(fa1, fb1, acc11, 0, 0, 0);
            if (more) {
                const int nxt = cur ^ 1;
                STAGE(&Albuf[nxt][row * 32 + wchunk * 8], a1, a2);
                STAGE(&Blbuf[nxt][row * 32 + wchunk * 8], b1, b2);
            }
            __syncthreads();
        }

        // write 64x64 logits tile to LDS (C layout: col=lane&15, row=quad*4+reg)
        {
            f32x4_t accs[2][2] = {{acc00, acc01}, {acc10, acc11}};
#pragma unroll
            for (int ti = 0; ti < 2; ++ti)
#pragma unroll
                for (int si = 0; si < 2; ++si)
#pragma unroll
                    for (int i = 0; i < 4; ++i)
                        logits[(32 * wr + 16 * ti + q * 4 + i) * 67
                               + 32 * wc + 16 * si + lm] = accs[ti][si][i];
        }
        __syncthreads();

        // online logsumexp: 4 partial scanners per row (16 cols each)
        {
            const int r = tid & 63;
            const int labr = tid_lds[r];
            float mloc = -INFINITY, lloc = 0.0f;
#pragma unroll
            for (int j0 = 0; j0 < 16; ++j0) {
                const int j = w * 16 + j0;
                const float x = logits[r * 67 + j] + adj_lds[j];
                const bool valid = (j < scount) && (sid_lds[j] != labr);
                if (valid) {
                    if (x > mloc) { lloc = lloc * __expf(mloc - x) + 1.0f; mloc = x; }
                    else          { lloc += __expf(x - mloc); }
                }
            }
            mpart[w][r] = mloc;
            lpart[w][r] = lloc;
        }
        __syncthreads();
        if (tid < 64) {
#pragma unroll
            for (int p = 0; p < 4; ++p) {
                const float mp = mpart[p][tid];
                const float lp = lpart[p][tid];
                if (lp > 0.0f) {
                    if (mp > m_run) { l_run = l_run * __expf(m_run - mp) + lp; m_run = mp; }
                    else            { l_run += lp * __expf(mp - m_run); }
                }
            }
        }
    }

    __syncthreads();
    if (tid < 64) {   // wave 0: finish loss per row, reduce, accumulate
        const float tl = true_lds[tid];
        const float M = fmaxf(m_run, tl);
        float loss = __logf(l_run * __expf(m_run - M) + __expf(tl - M)) + M - tl;
#pragma unroll
        for (int off = 32; off > 0; off >>= 1) loss += __shfl_xor(loss, off, 64);
        if (tid == 0) atomicAdd(accum, loss);
    }
}

__global__ void zero_accum_kernel(float* p) { *p = 0.0f; }

// Reference output dtype is float32 -> d_out is float* (round-1 bug: wrote
// a 2-byte bf16 into the 4-byte slot -> harness read ~0.0).
__global__ void finalize_kernel(const float* p, float* out) {
    out[0] = p[0] * (0.5f / (float)(BATCH * SEQLEN));
}

extern "C" void kernel_launch(void* const* d_in, const int* in_sizes, int n_in,
                              void* d_out, int out_size, void* d_ws, size_t ws_size,
                              hipStream_t stream) {
    const float* h      = (const float*)d_in[0];
    const int*   labels = (const int*)d_in[1];
    const int*   sids   = (const int*)d_in[2];
    const float* W      = (const float*)d_in[3];
    const float* bias   = (const float*)d_in[4];
    float* accum = (float*)d_ws;

    zero_accum_kernel<<<dim3(1), dim3(1), 0, stream>>>(accum);
    sampled_softmax_main<<<dim3(8, 32), dim3(256), 0, stream>>>(h, labels, sids, W, bias, accum);
    finalize_kernel<<<dim3(1), dim3(1), 0, stream>>>(accum, (float*)d_out);
}

// Round 3
// 454.124 us; speedup vs baseline: 1.6159x; 1.6159x over previous
//
#include <hip/hip_runtime.h>
#include <hip/hip_bf16.h>
#include <cmath>

#define BATCH 32
#define SEQLEN 512
#define NSAMP 1000
#define DMODEL 1024
#define NCHUNK 4          // s split into 4 chunks of 4 tiles (64 samples each)

typedef __bf16 bf16x8_t __attribute__((ext_vector_type(8)));
typedef float f32x4_t __attribute__((ext_vector_type(4)));

__device__ __forceinline__ unsigned pack_bf2(float lo, float hi) {
    unsigned ulo = __float_as_uint(lo);
    unsigned uhi = __float_as_uint(hi);
    ulo = (ulo + 0x7fffu + ((ulo >> 16) & 1u)) >> 16;
    uhi = (uhi + 0x7fffu + ((uhi >> 16) & 1u)) & 0xffff0000u;
    return (ulo & 0xffffu) | uhi;
}

// TF log-uniform sampler expected-count, log-domain (log1p to avoid cancellation)
__device__ __forceinline__ float log_expected_count(int id) {
    float idf = (float)id;
    float p = log1pf(1.0f / (idf + 1.0f)) * 0.09242316f; // 1/ln(50001)
    return logf(-expm1f(1000.0f * log1pf(-p)));
}

#define STAGE(dst, f1, f2)                                                     \
    do {                                                                       \
        uint4 _u;                                                              \
        _u.x = pack_bf2((f1).x, (f1).y);                                       \
        _u.y = pack_bf2((f1).z, (f1).w);                                       \
        _u.z = pack_bf2((f2).x, (f2).y);                                       \
        _u.w = pack_bf2((f2).z, (f2).w);                                       \
        *(uint4*)(dst) = _u;                                                   \
    } while (0)

// ---- prep: fused W-row gather->bf16 (+adj) and fp32 true-logit dot ----
// blocks [0, 8000): gather 4 rows of Wb each (32000 rows total)
// blocks [8000, 12096): true logits, 4 (b,t) rows each (16384 total)
__global__ __launch_bounds__(256) void prep_kernel(
    const float* __restrict__ h, const int* __restrict__ labels,
    const int* __restrict__ sids, const float* __restrict__ W,
    const float* __restrict__ bias, unsigned short* __restrict__ Wb,
    float* __restrict__ adjw, float* __restrict__ tlw)
{
    const int w = threadIdx.x >> 6, lane = threadIdx.x & 63;
    if (blockIdx.x < 8000) {
        const int row = blockIdx.x * 4 + w;            // b*1000+s
        const int sv = sids[row];
        const float4* src = (const float4*)(W + (size_t)sv * DMODEL);
        unsigned short* dst = Wb + (size_t)row * DMODEL;
#pragma unroll
        for (int j = 0; j < 4; ++j) {
            float4 v = src[lane + j * 64];
            uint2 u;
            u.x = pack_bf2(v.x, v.y);
            u.y = pack_bf2(v.z, v.w);
            *(uint2*)(dst + (lane + j * 64) * 4) = u;
        }
        if (lane == 0) adjw[row] = bias[sv] - log_expected_count(sv);
    } else {
        const int r = (blockIdx.x - 8000) * 4 + w;     // b*512+t
        const int lab = labels[r];
        const float4* hp = (const float4*)(h + (size_t)r * DMODEL);
        const float4* wp = (const float4*)(W + (size_t)lab * DMODEL);
        float s = 0.0f;
#pragma unroll
        for (int j = 0; j < 4; ++j) {
            float4 a = hp[lane + j * 64];
            float4 c = wp[lane + j * 64];
            s += a.x * c.x + a.y * c.y + a.z * c.z + a.w * c.w;
        }
#pragma unroll
        for (int off = 32; off > 0; off >>= 1) s += __shfl_xor(s, off, 64);
        if (lane == 0) tlw[r] = s + bias[lab] - log_expected_count(lab);
    }
}

// ---- main: 64-t-row x 256-sample tile GEMM + partial online LSE ----
__global__ __launch_bounds__(256) void sampled_softmax_main(
    const float* __restrict__ h, const int* __restrict__ labels,
    const int* __restrict__ sids, const unsigned short* __restrict__ Wb,
    const float* __restrict__ adjw,
    float* __restrict__ pm, float* __restrict__ pl)
{
    __shared__ __align__(16) unsigned short Albuf[2][64 * 32];
    __shared__ __align__(16) unsigned short Blbuf[2][64 * 32];
    __shared__ float logits[64 * 67];
    __shared__ int   tid_lds[64];
    __shared__ int   sid_lds[64];
    __shared__ float adj_lds[64];
    __shared__ float mpart[4][64];
    __shared__ float lpart[4][64];

    const int tile_t = blockIdx.x;   // 0..7
    const int bb     = blockIdx.y;   // 0..31
    const int chunk  = blockIdx.z;   // 0..3
    const int t0     = tile_t * 64;
    const int tid    = threadIdx.x;
    const int w      = tid >> 6;
    const int lane   = tid & 63;
    const int lm     = lane & 15;
    const int q      = lane >> 4;

    if (tid < 64) tid_lds[tid] = labels[bb * SEQLEN + t0 + tid];

    float m_run = -INFINITY, l_run = 0.0f;

    const int row    = tid >> 2;                 // staging row 0..63
    const int cg     = tid & 3;                  // 8-elem chunk 0..3
    const int wchunk = cg ^ (row & 3);           // XOR swizzle on write
    const int wr = w >> 1, wc = w & 1;
    const int ar0 = 32 * wr + lm;
    const int bc0 = 32 * wc + lm;
    const int achunk = (q ^ (lm & 3)) * 8;       // XOR swizzle on frag read
    const float* aG = h + ((size_t)(bb * SEQLEN + t0 + row)) * DMODEL + cg * 8;

    for (int lt = 0; lt < 4; ++lt) {
        const int s0 = (chunk * 4 + lt) * 64;
        const int scount = (NSAMP - s0 < 64) ? (NSAMP - s0) : 64;
        __syncthreads();   // protect sid/adj/logits reuse
        if (tid < 64) {
            const int s = s0 + tid;
            sid_lds[tid] = (s < NSAMP) ? sids[bb * NSAMP + s] : -1;
            adj_lds[tid] = (s < NSAMP) ? adjw[bb * NSAMP + s] : 0.0f;
        }
        int srow = s0 + row;
        if (srow > NSAMP - 1) srow = NSAMP - 1;  // clamp (masked later)
        const unsigned short* bG = Wb + (size_t)(bb * NSAMP + srow) * DMODEL + cg * 8;
        __syncthreads();

        f32x4_t acc00 = {0,0,0,0}, acc01 = {0,0,0,0};
        f32x4_t acc10 = {0,0,0,0}, acc11 = {0,0,0,0};

        {   // prologue: K-tile 0 -> buffer 0
            float4 a1 = *(const float4*)(aG);
            float4 a2 = *(const float4*)(aG + 4);
            uint4  bv = *(const uint4*)(bG);
            STAGE(&Albuf[0][row * 32 + wchunk * 8], a1, a2);
            *(uint4*)&Blbuf[0][row * 32 + wchunk * 8] = bv;
        }
        __syncthreads();

#pragma unroll 2
        for (int kt = 0; kt < 32; ++kt) {
            const int cur = kt & 1;
            float4 a1, a2; uint4 bv;
            const bool more = (kt + 1) < 32;
            if (more) {
                const float* ap = aG + (kt + 1) * 32;
                a1 = *(const float4*)(ap);
                a2 = *(const float4*)(ap + 4);
                bv = *(const uint4*)(bG + (kt + 1) * 32);
            }
            const unsigned short* Ab = Albuf[cur];
            const unsigned short* Bb = Blbuf[cur];
            bf16x8_t fa0 = *(const bf16x8_t*)(Ab + ar0 * 32 + achunk);
            bf16x8_t fa1 = *(const bf16x8_t*)(Ab + (ar0 + 16) * 32 + achunk);
            bf16x8_t fb0 = *(const bf16x8_t*)(Bb + bc0 * 32 + achunk);
            bf16x8_t fb1 = *(const bf16x8_t*)(Bb + (bc0 + 16) * 32 + achunk);
            acc00 = __builtin_amdgcn_mfma_f32_16x16x32_bf16(fa0, fb0, acc00, 0, 0, 0);
            acc01 = __builtin_amdgcn_mfma_f32_16x16x32_bf16(fa0, fb1, acc01, 0, 0, 0);
            acc10 = __builtin_amdgcn_mfma_f32_16x16x32_bf16(fa1, fb0, acc10, 0, 0, 0);
            acc11 = __builtin_amdgcn_mfma_f32_16x16x32_bf16(fa1, fb1, acc11, 0, 0, 0);
            if (more) {
                const int nxt = cur ^ 1;
                STAGE(&Albuf[nxt][row * 32 + wchunk * 8], a1, a2);
                *(uint4*)&Blbuf[nxt][row * 32 + wchunk * 8] = bv;
            }
            __syncthreads();
        }

        {   // C layout: col=lane&15, row=quad*4+reg
            f32x4_t accs[2][2] = {{acc00, acc01}, {acc10, acc11}};
#pragma unroll
            for (int ti = 0; ti < 2; ++ti)
#pragma unroll
                for (int si = 0; si < 2; ++si)
#pragma unroll
                    for (int i = 0; i < 4; ++i)
                        logits[(32 * wr + 16 * ti + q * 4 + i) * 67
                               + 32 * wc + 16 * si + lm] = accs[ti][si][i];
        }
        __syncthreads();

        {   // online LSE: 4 partial scanners per row (16 cols each)
            const int r = tid & 63;
            const int labr = tid_lds[r];
            float mloc = -INFINITY, lloc = 0.0f;
#pragma unroll
            for (int j0 = 0; j0 < 16; ++j0) {
                const int j = w * 16 + j0;
                const float x = logits[r * 67 + j] + adj_lds[j];
                const bool valid = (j < scount) && (sid_lds[j] != labr);
                if (valid) {
                    if (x > mloc) { lloc = lloc * __expf(mloc - x) + 1.0f; mloc = x; }
                    else          { lloc += __expf(x - mloc); }
                }
            }
            mpart[w][r] = mloc;
            lpart[w][r] = lloc;
        }
        __syncthreads();
        if (tid < 64) {
#pragma unroll
            for (int p = 0; p < 4; ++p) {
                const float mp = mpart[p][tid];
                const float lp = lpart[p][tid];
                if (lp > 0.0f) {
                    if (mp > m_run) { l_run = l_run * __expf(m_run - mp) + lp; m_run = mp; }
                    else            { l_run += lp * __expf(mp - m_run); }
                }
            }
        }
    }

    if (tid < 64) {
        const int idx = (bb * SEQLEN + t0 + tid) * NCHUNK + chunk;
        pm[idx] = m_run;
        pl[idx] = l_run;
    }
}

// ---- combine: merge 4 partial (m,l) + true logit -> per-block loss sums ----
__global__ __launch_bounds__(256) void combine_kernel(
    const float* __restrict__ pm, const float* __restrict__ pl,
    const float* __restrict__ tlw, float* __restrict__ bsum)
{
    __shared__ float wsum[4];
    const int tid = threadIdx.x;
    const int w = tid >> 6, lane = tid & 63;
    const int idx = blockIdx.x * 256 + tid;      // 0..16383
    float m = -INFINITY, l = 0.0f;
#pragma unroll
    for (int c = 0; c < NCHUNK; ++c) {
        const float mp = pm[idx * NCHUNK + c];
        const float lp = pl[idx * NCHUNK + c];
        if (lp > 0.0f) {
            if (mp > m) { l = l * __expf(m - mp) + lp; m = mp; }
            else        { l += lp * __expf(mp - m); }
        }
    }
    const float t = tlw[idx];
    const float M = fmaxf(m, t);
    float loss = __logf(l * __expf(m - M) + __expf(t - M)) + M - t;
#pragma unroll
    for (int off = 32; off > 0; off >>= 1) loss += __shfl_xor(loss, off, 64);
    if (lane == 0) wsum[w] = loss;
    __syncthreads();
    if (tid == 0) bsum[blockIdx.x] = wsum[0] + wsum[1] + wsum[2] + wsum[3];
}

__global__ void finalize_kernel(const float* __restrict__ bsum, float* __restrict__ out) {
    float v = bsum[threadIdx.x];
#pragma unroll
    for (int off = 32; off > 0; off >>= 1) v += __shfl_xor(v, off, 64);
    if (threadIdx.x == 0) out[0] = v * (0.5f / (float)(BATCH * SEQLEN));
}

extern "C" void kernel_launch(void* const* d_in, const int* in_sizes, int n_in,
                              void* d_out, int out_size, void* d_ws, size_t ws_size,
                              hipStream_t stream) {
    const float* h      = (const float*)d_in[0];
    const int*   labels = (const int*)d_in[1];
    const int*   sids   = (const int*)d_in[2];
    const float* W      = (const float*)d_in[3];
    const float* bias   = (const float*)d_in[4];

    // workspace layout (~66.3 MB, 16B-aligned offsets)
    char* base = (char*)d_ws;
    unsigned short* Wb = (unsigned short*)base;                 // 65,536,000
    float* adjw = (float*)(base + 65536000);                    //    128,000
    float* tlw  = (float*)(base + 65536000 + 128000);           //     65,536
    float* pmw  = (float*)(base + 65536000 + 128000 + 65536);   //    262,144
    float* plw  = (float*)(base + 65536000 + 128000 + 65536 + 262144);
    float* bsum = (float*)(base + 65536000 + 128000 + 65536 + 262144 + 262144);

    prep_kernel<<<dim3(12096), dim3(256), 0, stream>>>(h, labels, sids, W, bias, Wb, adjw, tlw);
    sampled_softmax_main<<<dim3(8, 32, NCHUNK), dim3(256), 0, stream>>>(
        h, labels, sids, Wb, adjw, pmw, plw);
    combine_kernel<<<dim3(64), dim3(256), 0, stream>>>(pmw, plw, tlw, bsum);
    finalize_kernel<<<dim3(1), dim3(64), 0, stream>>>(bsum, (float*)d_out);
}